// Round 6
// baseline (689.736 us; speedup 1.0000x reference)
//
#include <hip/hip_runtime.h>

// ---------------------------------------------------------------------------
// KAN 2-layer forward, round 6.
// vs r5 (GEMM1 272us: LDS-pipe serial floor ~1500cyc/step, 1 block/CU, MFMA
// only 27%): B fragments now load DIRECTLY from L2 to registers — the packed
// W layout [n][f*8+t] IS the MFMA B-frag layout (16B contiguous per lane).
// Deletes 64 of 104 LDS instrs/step + the DMA vmcnt-barrier coupling.
// LDS keeps only A (act staging, 2x8KB double-buffer, barrier waits lgkm
// only). Per-step pipes/SIMD: MFMA 1082 (top), L2-B 49 B/cyc/CU (<56 ceil),
// act 280 (interleaves under MFMA). Shape unchanged: BM=128, BN full-width,
// 512 thr, 8 waves 2m x 4n, wave 64x128, acc[4][8], split-K=2.
// ---------------------------------------------------------------------------

typedef short s16x8 __attribute__((ext_vector_type(8)));  // 8 bf16 = 4 VGPRs
typedef float f32x4 __attribute__((ext_vector_type(4)));

__device__ __forceinline__ unsigned pk2(float lo, float hi) {
  unsigned a = __float_as_uint(lo), b = __float_as_uint(hi);
  a = a + 0x7fffu + ((a >> 16) & 1u);
  b = b + 0x7fffu + ((b >> 16) & 1u);
  return __builtin_amdgcn_perm(b, a, 0x07060302u);  // {b.hi16, a.hi16}
}

__device__ __forceinline__ unsigned short f2bf(float f) {
  unsigned u = __float_as_uint(f);
  unsigned r = u + 0x7fffu + ((u >> 16) & 1u);
  return (unsigned short)(r >> 16);
}

// silu + 6 cubic B-spline bases (uniform extended grid, u = 1.5x+4.5, knots
// u=0..9; recursion ref-verified r1..r5). Packed bf16x8 [silu,b3_0..5,0].
__device__ __forceinline__ uint4 kan_act8(float x) {
  float e = __expf(-x);
  float s = x * __builtin_amdgcn_rcpf(1.0f + e);
  float u = fmaf(x, 1.5f, 4.5f);
  float d[10];
#pragma unroll
  for (int j = 0; j < 10; ++j) d[j] = u - (float)j;
  float b1[8];
#pragma unroll
  for (int j = 0; j < 8; ++j) b1[j] = fmaxf(0.0f, 1.0f - fabsf(d[j + 1]));
  float B2[7];
#pragma unroll
  for (int j = 0; j < 7; ++j) B2[j] = d[j] * b1[j] - d[j + 3] * b1[j + 1];
  float b3[6];
#pragma unroll
  for (int j = 0; j < 6; ++j)
    b3[j] = (d[j] * B2[j] - d[j + 4] * B2[j + 1]) * (1.0f / 6.0f);
  uint4 r;
  r.x = pk2(s, b3[0]);
  r.y = pk2(b3[1], b3[2]);
  r.z = pk2(b3[3], b3[4]);
  r.w = pk2(b3[5], 0.0f);
  return r;
}

// Pack weights: Wp[n][i*8+t] bf16 (plain layout — this is already the MFMA
// B-fragment layout). t=0 base_w, t=1..6 spline_w*scaler, t=7 zero.
// Rows n >= Nvalid are zero.
__global__ __launch_bounds__(256) void prep_w(
    const float* __restrict__ base_w, const float* __restrict__ spline_w,
    const float* __restrict__ scaler, short* __restrict__ Wp,
    int F, int Nvalid) {
  int i = blockIdx.x * 256 + threadIdx.x;
  int n = blockIdx.y;
  if (i >= F) return;
  s16x8 v;
#pragma unroll
  for (int k = 0; k < 8; ++k) v[k] = 0;
  if (n < Nvalid) {
    int idx = n * F + i;
    float sc = scaler[idx];
    v[0] = (short)f2bf(base_w[idx]);
#pragma unroll
    for (int k = 0; k < 6; ++k) v[1 + k] = (short)f2bf(spline_w[idx * 6 + k] * sc);
  }
  *(s16x8*)&Wp[((size_t)n * F + i) * 8] = v;
}

// Fused-activation GEMM. BM=128, BN in {512,256} = full width, BK=32
// (4 features). 512 threads = 8 waves (2m x 4n), wave tile 64 x BN/4.
// A: computed acts staged via LDS (double buffer, XOR bank swizzle).
// B: fragments loaded straight from global/L2 (packed W = frag layout).
// blockIdx.z = K-part; partial C -> Cp + z*pstride.
template <int BN>
__global__ __launch_bounds__(512, 2) void kan_gemm(
    const float* __restrict__ X, const short* __restrict__ W,
    float* __restrict__ Cp, int F, int span, long long pstride,
    int ldc, int ncols) {
  constexpr int NT = BN / 64;  // n-tiles per wave
  __shared__ __align__(16) short As[2][128 * 32];

  const int t    = threadIdx.x;
  const int lane = t & 63;
  const int w    = t >> 6;
  const int m0   = blockIdx.x * 128;
  const int f0   = blockIdx.z * span;
  const size_t K8 = (size_t)F * 8;  // W row stride (shorts)

  const int wrow = (w >> 2) * 64;
  const int wcol = (w & 3) * (BN / 4);
  const int mrow = lane & 15;
  const int q    = lane >> 4;
  const int qs   = (q ^ (mrow & 3)) * 8;

  int a_off[4];
#pragma unroll
  for (int it = 0; it < 4; ++it)
    a_off[it] = (wrow + it * 16 + mrow) * 32 + qs;

  // B fragment base: lane reads W[wcol + jt*16 + mrow][(f0 + ks*4 + q)*8 ..]
  const short* wb0 = W + (size_t)(wcol + mrow) * K8 + (size_t)(f0 + q) * 8;
  const size_t jstr = 16 * K8;  // +16 output rows per n-tile

  // A staging: one activation per thread per step (128 rows x 4 features)
  const int sr = t >> 2, sj = t & 3;
  const float* xq = X + (size_t)(m0 + sr) * F + f0 + sj;
  const int aw = sr * 32 + ((sj ^ (sr & 3)) * 8);

  f32x4 acc[4][NT] = {};
  const int nsteps = span >> 2;

  // prologue: act for step 0 into buffer 0; prefetch x for step 1
  float xn = *xq;
  {
    uint4 av = kan_act8(xn);
    *(uint4*)&As[0][aw] = av;
  }
  if (nsteps > 1) xn = xq[4];
  __syncthreads();

  for (int ks = 0; ks < nsteps; ++ks) {
    const int cb = ks & 1, nb = cb ^ 1;

    // B frags direct from L2 (no LDS, no barrier dependency)
    s16x8 bfr[NT];
#pragma unroll
    for (int jt = 0; jt < NT; ++jt)
      bfr[jt] = *(const s16x8*)(wb0 + jt * jstr + (size_t)ks * 32);

    s16x8 af[4];
#pragma unroll
    for (int it = 0; it < 4; ++it)
      af[it] = *(const s16x8*)&As[cb][a_off[it]];

#pragma unroll
    for (int b = 0; b < NT; ++b)
#pragma unroll
      for (int a = 0; a < 4; ++a)
        acc[a][b] = __builtin_amdgcn_mfma_f32_16x16x32_bf16(
            af[a], bfr[b], acc[a][b], 0, 0, 0);

    if (ks + 1 < nsteps) {
      uint4 av = kan_act8(xn);
      *(uint4*)&As[nb][aw] = av;
      if (ks + 2 < nsteps) xn = xq[(size_t)(ks + 2) * 4];
    }
    __syncthreads();
  }

  // C/D layout: col = lane&15, row = quad*4 + reg (verified r1/r3/r4/r5)
  float* cpt = Cp + (size_t)blockIdx.z * (size_t)pstride;
#pragma unroll
  for (int a = 0; a < 4; ++a) {
#pragma unroll
    for (int b = 0; b < NT; ++b) {
      int col = wcol + b * 16 + mrow;
      if (col < ncols) {
#pragma unroll
        for (int r = 0; r < 4; ++r) {
          int row = m0 + wrow + a * 16 + q * 4 + r;
          cpt[(size_t)row * ldc + col] = acc[a][b][r];
        }
      }
    }
  }
}

// h = LayerNorm(p0 + p1) over D=512, one wave per row.
__global__ __launch_bounds__(256) void ln_reduce(
    const float* __restrict__ p0, const float* __restrict__ p1,
    float* __restrict__ h, const float* __restrict__ gamma,
    const float* __restrict__ beta, int nparts) {
  int lane = threadIdx.x & 63;
  int wv   = threadIdx.x >> 6;
  int row  = blockIdx.x * 4 + wv;
  size_t base = (size_t)row * 512 + lane * 8;
  f32x4 v0 = *(const f32x4*)(p0 + base);
  f32x4 v1 = *(const f32x4*)(p0 + base + 4);
  if (nparts == 2) {
    f32x4 u0 = *(const f32x4*)(p1 + base);
    f32x4 u1 = *(const f32x4*)(p1 + base + 4);
#pragma unroll
    for (int k = 0; k < 4; ++k) { v0[k] += u0[k]; v1[k] += u1[k]; }
  }
  float s = 0.f, s2 = 0.f;
#pragma unroll
  for (int k = 0; k < 4; ++k) { s += v0[k] + v1[k]; s2 += v0[k]*v0[k] + v1[k]*v1[k]; }
#pragma unroll
  for (int m = 32; m >= 1; m >>= 1) {
    s  += __shfl_xor(s,  m, 64);
    s2 += __shfl_xor(s2, m, 64);
  }
  float mean = s * (1.0f / 512.0f);
  float var  = s2 * (1.0f / 512.0f) - mean * mean;
  float rstd = rsqrtf(var + 1e-5f);
  const f32x4 g0 = *(const f32x4*)(gamma + lane * 8);
  const f32x4 g1 = *(const f32x4*)(gamma + lane * 8 + 4);
  const f32x4 be0 = *(const f32x4*)(beta + lane * 8);
  const f32x4 be1 = *(const f32x4*)(beta + lane * 8 + 4);
#pragma unroll
  for (int k = 0; k < 4; ++k) {
    v0[k] = (v0[k] - mean) * rstd * g0[k] + be0[k];
    v1[k] = (v1[k] - mean) * rstd * g1[k] + be1[k];
  }
  *(f32x4*)(h + base) = v0;
  *(f32x4*)(h + base + 4) = v1;
}

// out[b][c<229] = p0[b][c] (+ p1[b][c]) from 256-wide padded partials.
__global__ __launch_bounds__(256) void out_reduce(
    const float* __restrict__ p0, const float* __restrict__ p1,
    float* __restrict__ out, int nparts) {
  int idx = blockIdx.x * 256 + threadIdx.x;
  int row = idx >> 8;
  int c   = idx & 255;
  float v = p0[idx];
  if (nparts == 2) v += p1[idx];
  if (c < 229) out[(size_t)row * 229 + c] = v;
}

extern "C" void kernel_launch(void* const* d_in, const int* in_sizes, int n_in,
                              void* d_out, int out_size, void* d_ws, size_t ws_size,
                              hipStream_t stream) {
  const float* x         = (const float*)d_in[0];
  const float* base_w1   = (const float*)d_in[1];
  const float* spline_w1 = (const float*)d_in[2];
  const float* scaler1   = (const float*)d_in[3];
  const float* ln_gamma  = (const float*)d_in[4];
  const float* ln_beta   = (const float*)d_in[5];
  const float* base_w2   = (const float*)d_in[6];
  const float* spline_w2 = (const float*)d_in[7];
  const float* scaler2   = (const float*)d_in[8];
  float* out = (float*)d_out;

  const int B = 16384, D_IN = 1280, D_HID = 512, D_OUT = 229;

  // ws layout: W1p | W2p | h | p0 | p1   (~113 MB with parts=2)
  const size_t szW1 = (size_t)D_HID * D_IN * 8 * 2;   // 10,485,760
  const size_t szW2 = (size_t)256 * D_HID * 8 * 2;    //  2,097,152
  const size_t szH  = (size_t)B * D_HID * 4;          // 33,554,432
  const size_t szP  = (size_t)B * 512 * 4;            // 33,554,432 slot
  char* ws = (char*)d_ws;
  short* W1p = (short*)ws;
  short* W2p = (short*)(ws + szW1);
  float* h   = (float*)(ws + szW1 + szW2);
  float* p0  = (float*)(ws + szW1 + szW2 + szH);
  float* p1  = (float*)(ws + szW1 + szW2 + szH + szP);

  const int parts = (ws_size >= szW1 + szW2 + szH + 2 * szP) ? 2 : 1;
  const long long pstride = (long long)(szP / 4);  // elements = slot size

  prep_w<<<dim3(D_IN / 256, D_HID), 256, 0, stream>>>(
      base_w1, spline_w1, scaler1, W1p, D_IN, D_HID);
  prep_w<<<dim3(D_HID / 256, 256), 256, 0, stream>>>(
      base_w2, spline_w2, scaler2, W2p, D_HID, D_OUT);

  // layer 1: (16384 x 1280) -> split-K partials (16384 x 512) x parts
  kan_gemm<512><<<dim3(B / 128, 1, parts), 512, 0, stream>>>(
      x, W1p, p0, D_IN, D_IN / parts, pstride, D_HID, D_HID);

  ln_reduce<<<dim3(B / 4), 256, 0, stream>>>(p0, p1, h, ln_gamma, ln_beta, parts);

  // layer 2: (16384 x 512) -> split-K partials (16384 x 256) x parts
  kan_gemm<256><<<dim3(B / 128, 1, parts), 512, 0, stream>>>(
      h, W2p, p0, D_HID, D_HID / parts, pstride, 256, 256);

  out_reduce<<<dim3(B * 256 / 256), 256, 0, stream>>>(p0, p1, out, parts);
}

// Round 7
// 441.457 us; speedup vs baseline: 1.5624x; 1.5624x over previous
//
#include <hip/hip_runtime.h>

// ---------------------------------------------------------------------------
// KAN 2-layer forward, round 7.
// Evidence r5 vs r6: LDS-staged B has the right cache traffic (1.3 GB,
// coalesced DMA) but r5 ran 1 block/CU (72KB... 80KB LDS) and serialized at
// the per-step barrier (4080 cyc/step vs ~1500 busy). r6's direct-L2 B was a
// request-rate wall (16 scattered 64B lines per load instr, 2.7 GB traffic).
// r7 = r5 structure sized for 2 blocks/CU:
//   BM=64, 256 thr = 4 waves all n-major (wave 64 x BN/4) -> B LDS reads have
//   ZERO duplication, act once per block via A-LDS. LDS 72KB -> 2 blocks/CU;
//   acc 128 AGPR + ~100 VGPR < 256 -> no spill. B via global_load_lds DMA
//   (W pre-swizzled in HBM so linear DMA is bank-conflict-free), A explicit
//   XOR swizzle. Double-buffered, one barrier per step; the two co-resident
//   blocks overlap MFMA/LDS/VALU phases across their barriers (m114).
// ---------------------------------------------------------------------------

typedef short s16x8 __attribute__((ext_vector_type(8)));  // 8 bf16 = 4 VGPRs
typedef float f32x4 __attribute__((ext_vector_type(4)));

__device__ __forceinline__ void dma16(const void* g, void* l) {
  __builtin_amdgcn_global_load_lds(
      (const __attribute__((address_space(1))) unsigned int*)g,
      (__attribute__((address_space(3))) unsigned int*)l, 16, 0, 0);
}

__device__ __forceinline__ unsigned pk2(float lo, float hi) {
  unsigned a = __float_as_uint(lo), b = __float_as_uint(hi);
  a = a + 0x7fffu + ((a >> 16) & 1u);
  b = b + 0x7fffu + ((b >> 16) & 1u);
  return __builtin_amdgcn_perm(b, a, 0x07060302u);  // {b.hi16, a.hi16}
}

__device__ __forceinline__ unsigned short f2bf(float f) {
  unsigned u = __float_as_uint(f);
  unsigned r = u + 0x7fffu + ((u >> 16) & 1u);
  return (unsigned short)(r >> 16);
}

// silu + 6 cubic B-spline bases (uniform extended grid, u = 1.5x+4.5, knots
// u=0..9; recursion ref-verified r1..r6). Packed bf16x8 [silu,b3_0..5,0].
__device__ __forceinline__ uint4 kan_act8(float x) {
  float e = __expf(-x);
  float s = x * __builtin_amdgcn_rcpf(1.0f + e);
  float u = fmaf(x, 1.5f, 4.5f);
  float d[10];
#pragma unroll
  for (int j = 0; j < 10; ++j) d[j] = u - (float)j;
  float b1[8];
#pragma unroll
  for (int j = 0; j < 8; ++j) b1[j] = fmaxf(0.0f, 1.0f - fabsf(d[j + 1]));
  float B2[7];
#pragma unroll
  for (int j = 0; j < 7; ++j) B2[j] = d[j] * b1[j] - d[j + 3] * b1[j + 1];
  float b3[6];
#pragma unroll
  for (int j = 0; j < 6; ++j)
    b3[j] = (d[j] * B2[j] - d[j + 4] * B2[j + 1]) * (1.0f / 6.0f);
  uint4 r;
  r.x = pk2(s, b3[0]);
  r.y = pk2(b3[1], b3[2]);
  r.z = pk2(b3[3], b3[4]);
  r.w = pk2(b3[5], 0.0f);
  return r;
}

// Pack weights with the bank swizzle baked in: feature i of row n stored at
// chunk position p = (i & ~3) | ((i & 3) ^ (n & 3)); t=0 base_w,
// t=1..6 spline_w*scaler, t=7 zero. Rows n >= Nvalid are zero.
__global__ __launch_bounds__(256) void prep_w(
    const float* __restrict__ base_w, const float* __restrict__ spline_w,
    const float* __restrict__ scaler, short* __restrict__ Wp,
    int F, int Nvalid) {
  int i = blockIdx.x * 256 + threadIdx.x;
  int n = blockIdx.y;
  if (i >= F) return;
  s16x8 v;
#pragma unroll
  for (int k = 0; k < 8; ++k) v[k] = 0;
  if (n < Nvalid) {
    int idx = n * F + i;
    float sc = scaler[idx];
    v[0] = (short)f2bf(base_w[idx]);
#pragma unroll
    for (int k = 0; k < 6; ++k) v[1 + k] = (short)f2bf(spline_w[idx * 6 + k] * sc);
  }
  int p = (i & ~3) | ((i & 3) ^ (n & 3));
  *(s16x8*)&Wp[((size_t)n * F + p) * 8] = v;
}

// Fused-activation GEMM. BM=64, BN in {512,256} full width, BK=32 (4 feats).
// 256 threads = 4 waves, all n-major: wave w covers cols [w*BN/4, +BN/4),
// NT = BN/64 n-tiles, acc[4][NT]. blockIdx.z = K-part -> Cp + z*pstride.
template <int BN>
__global__ __launch_bounds__(256, 2) void kan_gemm(
    const float* __restrict__ X, const short* __restrict__ W,
    float* __restrict__ Cp, int F, int span, long long pstride,
    int ldc, int ncols) {
  constexpr int NT = BN / 64;  // n-tiles per wave
  constexpr int IE = BN / 64;  // DMA issues per wave per step (16 rows each)
  __shared__ __align__(16) short As[2][64 * 32];
  __shared__ __align__(16) short Bs[2][BN * 32];

  const int t    = threadIdx.x;
  const int lane = t & 63;
  const int w    = t >> 6;
  const int m0   = blockIdx.x * 64;
  const int f0   = blockIdx.z * span;

  const int wcol = w * (BN / 4);
  const int mrow = lane & 15;
  const int q    = lane >> 4;
  const int qs   = (q ^ (mrow & 3)) * 8;

  int a_off[4], b_off[NT];
#pragma unroll
  for (int it = 0; it < 4; ++it)
    a_off[it] = (it * 16 + mrow) * 32 + qs;
#pragma unroll
  for (int jt = 0; jt < NT; ++jt)
    b_off[jt] = (wcol + jt * 16 + mrow) * 32 + qs;

  // A staging: one activation per thread per step (64 rows x 4 features)
  const int sr = t >> 2, sj = t & 3;
  const float* xq = X + (size_t)(m0 + sr) * F + f0 + sj;
  const int aw = sr * 32 + ((sj ^ (sr & 3)) * 8);

  // B DMA: wave w covers Bs rows [w*BN/4, +BN/4), 16 rows per issue;
  // lane l -> (row l>>2, chunk l&3); LDS dest = uniform base + lane*16B.
  const int drow = w * (BN / 4) + (lane >> 2);
  const int dchk = lane & 3;
  const char* wg = (const char*)W + ((size_t)drow * F + f0 + dchk) * 16;
  const size_t gistr = (size_t)16 * F * 16;  // +16 W rows, bytes

  f32x4 acc[4][NT] = {};
  const int nsteps = span >> 2;

  // prologue: stage step 0; prefetch x for step 1
  float xn = *xq;
#pragma unroll
  for (int e = 0; e < IE; ++e)
    dma16(wg + e * gistr, &Bs[0][(w * (BN / 4) + e * 16) * 32]);
  {
    uint4 av = kan_act8(xn);
    *(uint4*)&As[0][aw] = av;
  }
  if (nsteps > 1) xn = xq[4];
  __syncthreads();

  for (int ks = 0; ks < nsteps; ++ks) {
    const int cb = ks & 1, nb = cb ^ 1;
    const bool more = (ks + 1 < nsteps);
    if (more) {
#pragma unroll
      for (int e = 0; e < IE; ++e)
        dma16(wg + (size_t)(ks + 1) * 64 + e * gistr,
              &Bs[nb][(w * (BN / 4) + e * 16) * 32]);
    }

    s16x8 af[4], bfr[NT];
#pragma unroll
    for (int it = 0; it < 4; ++it)
      af[it] = *(const s16x8*)&As[cb][a_off[it]];
#pragma unroll
    for (int jt = 0; jt < NT; ++jt)
      bfr[jt] = *(const s16x8*)&Bs[cb][b_off[jt]];
#pragma unroll
    for (int b = 0; b < NT; ++b)
#pragma unroll
      for (int a = 0; a < 4; ++a)
        acc[a][b] = __builtin_amdgcn_mfma_f32_16x16x32_bf16(
            af[a], bfr[b], acc[a][b], 0, 0, 0);

    if (more) {
      uint4 av = kan_act8(xn);
      *(uint4*)&As[nb][aw] = av;
      if (ks + 2 < nsteps) xn = xq[(size_t)(ks + 2) * 4];
    }
    __syncthreads();  // also drains DMA vmcnt before next step's reads
  }

  // C/D layout: col = lane&15, row = quad*4 + reg (verified r1..r6)
  float* cpt = Cp + (size_t)blockIdx.z * (size_t)pstride;
#pragma unroll
  for (int a = 0; a < 4; ++a) {
#pragma unroll
    for (int b = 0; b < NT; ++b) {
      int col = wcol + b * 16 + mrow;
      if (col < ncols) {
#pragma unroll
        for (int r = 0; r < 4; ++r) {
          int row = m0 + a * 16 + q * 4 + r;
          cpt[(size_t)row * ldc + col] = acc[a][b][r];
        }
      }
    }
  }
}

// h = LayerNorm(p0 + p1) over D=512, one wave per row.
__global__ __launch_bounds__(256) void ln_reduce(
    const float* __restrict__ p0, const float* __restrict__ p1,
    float* __restrict__ h, const float* __restrict__ gamma,
    const float* __restrict__ beta, int nparts) {
  int lane = threadIdx.x & 63;
  int wv   = threadIdx.x >> 6;
  int row  = blockIdx.x * 4 + wv;
  size_t base = (size_t)row * 512 + lane * 8;
  f32x4 v0 = *(const f32x4*)(p0 + base);
  f32x4 v1 = *(const f32x4*)(p0 + base + 4);
  if (nparts == 2) {
    f32x4 u0 = *(const f32x4*)(p1 + base);
    f32x4 u1 = *(const f32x4*)(p1 + base + 4);
#pragma unroll
    for (int k = 0; k < 4; ++k) { v0[k] += u0[k]; v1[k] += u1[k]; }
  }
  float s = 0.f, s2 = 0.f;
#pragma unroll
  for (int k = 0; k < 4; ++k) { s += v0[k] + v1[k]; s2 += v0[k]*v0[k] + v1[k]*v1[k]; }
#pragma unroll
  for (int m = 32; m >= 1; m >>= 1) {
    s  += __shfl_xor(s,  m, 64);
    s2 += __shfl_xor(s2, m, 64);
  }
  float mean = s * (1.0f / 512.0f);
  float var  = s2 * (1.0f / 512.0f) - mean * mean;
  float rstd = rsqrtf(var + 1e-5f);
  const f32x4 g0 = *(const f32x4*)(gamma + lane * 8);
  const f32x4 g1 = *(const f32x4*)(gamma + lane * 8 + 4);
  const f32x4 be0 = *(const f32x4*)(beta + lane * 8);
  const f32x4 be1 = *(const f32x4*)(beta + lane * 8 + 4);
#pragma unroll
  for (int k = 0; k < 4; ++k) {
    v0[k] = (v0[k] - mean) * rstd * g0[k] + be0[k];
    v1[k] = (v1[k] - mean) * rstd * g1[k] + be1[k];
  }
  *(f32x4*)(h + base) = v0;
  *(f32x4*)(h + base + 4) = v1;
}

// out[b][c<229] = p0[b][c] (+ p1[b][c]) from 256-wide padded partials.
__global__ __launch_bounds__(256) void out_reduce(
    const float* __restrict__ p0, const float* __restrict__ p1,
    float* __restrict__ out, int nparts) {
  int idx = blockIdx.x * 256 + threadIdx.x;
  int row = idx >> 8;
  int c   = idx & 255;
  float v = p0[idx];
  if (nparts == 2) v += p1[idx];
  if (c < 229) out[(size_t)row * 229 + c] = v;
}

extern "C" void kernel_launch(void* const* d_in, const int* in_sizes, int n_in,
                              void* d_out, int out_size, void* d_ws, size_t ws_size,
                              hipStream_t stream) {
  const float* x         = (const float*)d_in[0];
  const float* base_w1   = (const float*)d_in[1];
  const float* spline_w1 = (const float*)d_in[2];
  const float* scaler1   = (const float*)d_in[3];
  const float* ln_gamma  = (const float*)d_in[4];
  const float* ln_beta   = (const float*)d_in[5];
  const float* base_w2   = (const float*)d_in[6];
  const float* spline_w2 = (const float*)d_in[7];
  const float* scaler2   = (const float*)d_in[8];
  float* out = (float*)d_out;

  const int B = 16384, D_IN = 1280, D_HID = 512, D_OUT = 229;

  // ws layout: W1p | W2p | h | p0 | p1   (~113 MB with parts=2)
  const size_t szW1 = (size_t)D_HID * D_IN * 8 * 2;   // 10,485,760
  const size_t szW2 = (size_t)256 * D_HID * 8 * 2;    //  2,097,152
  const size_t szH  = (size_t)B * D_HID * 4;          // 33,554,432
  const size_t szP  = (size_t)B * 512 * 4;            // 33,554,432 slot
  char* ws = (char*)d_ws;
  short* W1p = (short*)ws;
  short* W2p = (short*)(ws + szW1);
  float* h   = (float*)(ws + szW1 + szW2);
  float* p0  = (float*)(ws + szW1 + szW2 + szH);
  float* p1  = (float*)(ws + szW1 + szW2 + szH + szP);

  const int parts = (ws_size >= szW1 + szW2 + szH + 2 * szP) ? 2 : 1;
  const long long pstride = (long long)(szP / 4);  // elements = slot size

  prep_w<<<dim3(D_IN / 256, D_HID), 256, 0, stream>>>(
      base_w1, spline_w1, scaler1, W1p, D_IN, D_HID);
  prep_w<<<dim3(D_HID / 256, 256), 256, 0, stream>>>(
      base_w2, spline_w2, scaler2, W2p, D_HID, D_OUT);

  // layer 1: (16384 x 1280) -> split-K partials (16384 x 512) x parts
  kan_gemm<512><<<dim3(B / 64, 1, parts), 256, 0, stream>>>(
      x, W1p, p0, D_IN, D_IN / parts, pstride, D_HID, D_HID);

  ln_reduce<<<dim3(B / 4), 256, 0, stream>>>(p0, p1, h, ln_gamma, ln_beta, parts);

  // layer 2: (16384 x 512) -> split-K partials (16384 x 256) x parts
  kan_gemm<256><<<dim3(B / 64, 1, parts), 256, 0, stream>>>(
      h, W2p, p0, D_HID, D_HID / parts, pstride, 256, 256);

  out_reduce<<<dim3(B * 256 / 256), 256, 0, stream>>>(p0, p1, out, parts);
}